// Round 20
// baseline (1015.700 us; speedup 1.0000x reference)
//
#include <hip/hip_runtime.h>
#include <hip/hip_bf16.h>
#include <math.h>

#define BB 32
#define TT 12
#define NN 512
#define HH 64
#define DIN 65
#define MSUB 96
#define RTOT 16384
#define PSUB 5
#define BSTG 5120      // f16 per B staging buffer (10 subtiles x 512)

typedef _Float16 f16;
typedef f16 f16x4 __attribute__((ext_vector_type(4)));
typedef f16 f16x8 __attribute__((ext_vector_type(8)));
typedef float f32x4 __attribute__((ext_vector_type(4)));

#define GLD_LDS16(g, l) \
    __builtin_amdgcn_global_load_lds((const __attribute__((address_space(1))) void*)(g), \
                                     (__attribute__((address_space(3))) void*)(l), 16, 0, 0)

__device__ __forceinline__ size_t bf_addr(int j, int b, int p) {
    return ((size_t)(((j >> 5) * 32 + b) * PSUB + (p >> 4)) * 64 + ((j >> 3) & 3) * 16 + (p & 15)) * 8 + (j & 7);
}

__global__ __launch_bounds__(256) void conv_a(const float* __restrict__ P, f16* __restrict__ Af) {
    int u = blockIdx.x * 256 + threadIdx.x;
    int lane = u & 63;
    int su = u >> 6;
    int ks = su / MSUB, ms = su - ks * MSUB;
    int m = ms * 16 + (lane & 15);
    int k = ks * 32 + (lane >> 4) * 8;
    const float* src = &P[(size_t)m * 512 + k];
    f16x8 v;
#pragma unroll
    for (int i = 0; i < 8; ++i) v[i] = (f16)src[i];
    *(f16x8*)&Af[(size_t)u * 8] = v;
}

__global__ __launch_bounds__(256) void conv_w(const float* __restrict__ W, int O, int OS,
                                              f16* __restrict__ Wf) {
    int u = blockIdx.x * 256 + threadIdx.x;
    if (u >= 8 * OS * 64) return;
    int lane = u & 63, slot = u >> 6;
    int s = slot / OS, os = slot - s * OS;
    int o = os * 16 + (lane & 15);
    int g = lane >> 4;
    f16x8 v;
#pragma unroll
    for (int i = 0; i < 8; ++i) {
        int f = 2 * s + (i >= 4 ? 1 : 0);
        int kl = f / 5, ps = f - kl * 5;
        int p = ps * 16 + 4 * g + (i & 3);
        v[i] = (f < 15 && p < 65) ? (f16)W[(size_t)(kl * 65 + p) * O + o] : (f16)0.f;
    }
    *(f16x8*)&Wf[(size_t)u * 8] = v;
}

__global__ __launch_bounds__(256) void upd_x(const float* __restrict__ x, int t,
                                             f16* __restrict__ Bf) {
    int idx = blockIdx.x * 256 + threadIdx.x;
    if (idx >= RTOT) return;
    int b = idx >> 9, n = idx & 511;
    Bf[bf_addr(n, b, 0)] = (f16)x[((size_t)b * TT + t) * NN + n];
}

// B staging for 2-wave blocks: 10 subtiles, uniform 5 per wave
__device__ __forceinline__ void stage_b(const f16* __restrict__ BfIn, f16* __restrict__ lds,
                                        int b, int wave, int lane, int buf, int it) {
#pragma unroll
    for (int qi = 0; qi < 5; ++qi) {
        int q = qi * 2 + wave;  // 0..9
        int ksl = q / 5, ps = q - ksl * 5;
        const f16* src = &BfIn[((size_t)(((it * 2 + ksl) * 32 + b) * PSUB + ps) * 64 + lane) * 8];
        GLD_LDS16(src, &lds[buf * BSTG + q * 512 + lane * 8]);
    }
}

// A fragments: 6 per wave per K64-step; wave owns msub = k*32 + mb2*2 + wave
__device__ __forceinline__ void load_a(const f16* __restrict__ Af, f16x8 (&a)[6],
                                       int mb2, int wave, int lane, int it) {
#pragma unroll
    for (int s = 0; s < 2; ++s)
#pragma unroll
        for (int k = 0; k < 3; ++k)
            a[s * 3 + k] = *(const f16x8*)&Af[((size_t)((it * 2 + s) * MSUB + k * 32 + mb2 * 2 + wave) * 64 + lane) * 8];
}

__device__ __forceinline__ void compute_step(const f16* __restrict__ lds, int buf, int lane,
                                             const f16x8 (&a)[6], f32x4 (&acc)[15]) {
#pragma unroll
    for (int s = 0; s < 2; ++s) {
        f16x8 bfr[5];
#pragma unroll
        for (int ps = 0; ps < 5; ++ps)
            bfr[ps] = *(const f16x8*)&lds[buf * BSTG + (s * 5 + ps) * 512 + lane * 8];
#pragma unroll
        for (int k = 0; k < 3; ++k)
#pragma unroll
            for (int ps = 0; ps < 5; ++ps)
                acc[k * 5 + ps] = __builtin_amdgcn_mfma_f32_16x16x32_f16(bfr[ps], a[s * 3 + k], acc[k * 5 + ps], 0, 0, 0);
    }
}

// 3-buffer counted-vmcnt pipeline, 8 K64-steps, one raw barrier per step.
// Per wave per iter: 5 B-loads + 6 A-loads. At wait(it): loads newer than stage_b(it)
// = loadA(it)(6) + stage(it+1)(5) + loadA(it+1)(6) = 17 -> vmcnt(17); last iter: 6.
// A-register readiness is enforced separately by compiler-inserted waits (reg deps).
__device__ __forceinline__ void gcn_mm(const f16* __restrict__ Af,
                                       const f16* __restrict__ BfIn,
                                       f16* __restrict__ lds,
                                       int b, int mb2, int wave, int lane,
                                       f32x4 (&acc)[15]) {
    f16x8 a0[6], a1[6], a2[6];
    stage_b(BfIn, lds, b, wave, lane, 0, 0);
    load_a(Af, a0, mb2, wave, lane, 0);
    stage_b(BfIn, lds, b, wave, lane, 1, 1);
    load_a(Af, a1, mb2, wave, lane, 1);
#pragma unroll
    for (int it = 0; it < 8; ++it) {
        if (it < 7) {
            asm volatile("s_waitcnt vmcnt(17)" ::: "memory");
        } else {
            asm volatile("s_waitcnt vmcnt(6)" ::: "memory");
        }
        __builtin_amdgcn_sched_barrier(0);
        __builtin_amdgcn_s_barrier();
        __builtin_amdgcn_sched_barrier(0);
        if (it + 2 < 8) {
            stage_b(BfIn, lds, b, wave, lane, (it + 2) % 3, it + 2);
            if ((it + 2) % 3 == 0)      load_a(Af, a0, mb2, wave, lane, it + 2);
            else if ((it + 2) % 3 == 1) load_a(Af, a1, mb2, wave, lane, it + 2);
            else                        load_a(Af, a2, mb2, wave, lane, it + 2);
        }
        __builtin_amdgcn_sched_barrier(0);
        if (it % 3 == 0)      compute_step(lds, 0, lane, a0, acc);
        else if (it % 3 == 1) compute_step(lds, 1, lane, a1, acc);
        else                  compute_step(lds, 2, lane, a2, acc);
    }
}

__device__ __forceinline__ void build_ad(const f32x4 (&acc)[15], f16x8 (&ad)[8]) {
#pragma unroll
    for (int s = 0; s < 8; ++s)
#pragma unroll
        for (int i = 0; i < 4; ++i) {
            ad[s][i] = (f16)acc[2 * s][i];
            ad[s][4 + i] = (s < 7) ? (f16)acc[2 * s + 1][i] : (f16)0.f;
        }
}

// 512 blocks x 128 threads (2 waves): 2 blocks/CU -> cross-block latency cover.
// blockIdx = mb2*32 + b: XCD = b%8 (32 divides 512), Bf stays XCD-local.
__global__ __launch_bounds__(128, 1) void fused_gates(const f16* __restrict__ Af,
                                                      const f16* __restrict__ BfIn,
                                                      f16* __restrict__ BfOut,
                                                      const f16* __restrict__ Wf,
                                                      const float* __restrict__ bias,
                                                      const float* __restrict__ hf,
                                                      float* __restrict__ zf) {
    __shared__ f16 lds[3 * BSTG];
    int tid = threadIdx.x, wave = tid >> 6, lane = tid & 63;
    int b = blockIdx.x & 31, mb2 = blockIdx.x >> 5;

    f32x4 acc[15] = {};
    gcn_mm(Af, BfIn, lds, b, mb2, wave, lane, acc);

    f16x8 ad[8];
    build_ad(acc, ad);

    // dense: W direct global->VGPR; exposed latency covered by co-resident block
    f32x4 acc2[8] = {};
#pragma unroll
    for (int s = 0; s < 8; ++s)
#pragma unroll
        for (int os = 0; os < 8; ++os) {
            f16x8 w = *(const f16x8*)&Wf[((size_t)(s * 8 + os) * 64 + lane) * 8];
            acc2[os] = __builtin_amdgcn_mfma_f32_16x16x32_f16(ad[s], w, acc2[os], 0, 0, 0);
        }

    int o_l = lane & 15, g = lane >> 4;
    int node0 = mb2 * 32 + wave * 16;
    int rf = b * 32 + mb2 * 2 + wave;
#pragma unroll
    for (int os = 0; os < 4; ++os) {
        f32x4 v;
#pragma unroll
        for (int rI = 0; rI < 4; ++rI)
            v[rI] = 1.f / (1.f + expf(-(acc2[os][rI] + bias[os * 16 + o_l])));
        *(f32x4*)&zf[((size_t)(rf * 4 + os) * 64 + lane) * 4] = v;
    }
#pragma unroll
    for (int os = 4; os < 8; ++os) {
        int osh = os - 4;
        f32x4 hv = *(const f32x4*)&hf[((size_t)(rf * 4 + osh) * 64 + lane) * 4];
        f16x4 st;
#pragma unroll
        for (int rI = 0; rI < 4; ++rI) {
            float rr = 1.f / (1.f + expf(-(acc2[os][rI] + bias[64 + osh * 16 + o_l])));
            st[rI] = (f16)(rr * hv[rI]);
        }
        *(f16x4*)&BfOut[bf_addr(node0 + 4 * g, b, 1 + osh * 16 + o_l)] = st;
    }
    if (tid < 32) {
        int n = mb2 * 32 + tid;
        BfOut[bf_addr(n, b, 0)] = BfIn[bf_addr(n, b, 0)];
    }
}

__global__ __launch_bounds__(128, 1) void fused_cand(const f16* __restrict__ Af,
                                                     const f16* __restrict__ BfIn,
                                                     f16* __restrict__ BfOut,
                                                     const f16* __restrict__ Wf,
                                                     const float* __restrict__ bias,
                                                     const float* __restrict__ zf,
                                                     float* __restrict__ hf,
                                                     const float* __restrict__ xnext, int tnext,
                                                     const float* __restrict__ Wp,
                                                     const float* __restrict__ bp,
                                                     float* __restrict__ outp, int t, int hor,
                                                     int mode) {
    __shared__ f16 lds[3 * BSTG];
    int tid = threadIdx.x, wave = tid >> 6, lane = tid & 63;
    int b = blockIdx.x & 31, mb2 = blockIdx.x >> 5;

    f32x4 acc[15] = {};
    gcn_mm(Af, BfIn, lds, b, mb2, wave, lane, acc);

    f16x8 ad[8];
    build_ad(acc, ad);

    f32x4 acc2[4] = {};
#pragma unroll
    for (int s = 0; s < 8; ++s)
#pragma unroll
        for (int os = 0; os < 4; ++os) {
            f16x8 w = *(const f16x8*)&Wf[((size_t)(s * 4 + os) * 64 + lane) * 8];
            acc2[os] = __builtin_amdgcn_mfma_f32_16x16x32_f16(ad[s], w, acc2[os], 0, 0, 0);
        }

    int o_l = lane & 15, g = lane >> 4;
    int node0 = mb2 * 32 + wave * 16;
    int rf = b * 32 + mb2 * 2 + wave;
    float pp[4] = {0.f, 0.f, 0.f, 0.f};
#pragma unroll
    for (int os = 0; os < 4; ++os) {
        int o = os * 16 + o_l;
        float wp = mode ? Wp[o] : 0.f;
        f32x4 zv = *(const f32x4*)&zf[((size_t)(rf * 4 + os) * 64 + lane) * 4];
        f32x4 hv = *(const f32x4*)&hf[((size_t)(rf * 4 + os) * 64 + lane) * 4];
        f32x4 hn;
        f16x4 st;
#pragma unroll
        for (int rI = 0; rI < 4; ++rI) {
            float hc = tanhf(acc2[os][rI] + bias[o]);
            hn[rI] = (1.f - zv[rI]) * hv[rI] + zv[rI] * hc;
            pp[rI] += hn[rI] * wp;
            st[rI] = (f16)hn[rI];
        }
        *(f32x4*)&hf[((size_t)(rf * 4 + os) * 64 + lane) * 4] = hn;
        *(f16x4*)&BfOut[bf_addr(node0 + 4 * g, b, 1 + o)] = st;
    }
    if (mode) {
#pragma unroll
        for (int m = 1; m < 16; m <<= 1)
#pragma unroll
            for (int rI = 0; rI < 4; ++rI) pp[rI] += __shfl_xor(pp[rI], m, 64);
        if (o_l == 0) {
            int n0 = node0 + 4 * g;
            float4 ov;
            f16x4 pv;
            ov.x = pp[0] + bp[0]; ov.y = pp[1] + bp[0];
            ov.z = pp[2] + bp[0]; ov.w = pp[3] + bp[0];
            pv[0] = (f16)ov.x; pv[1] = (f16)ov.y; pv[2] = (f16)ov.z; pv[3] = (f16)ov.w;
            *(float4*)&outp[((size_t)b * hor + t) * NN + n0] = ov;
            *(f16x4*)&BfOut[bf_addr(n0, b, 0)] = pv;
        }
    } else {
        if (o_l == 0) {
            int n0 = node0 + 4 * g;
            f16x4 pv;
#pragma unroll
            for (int rI = 0; rI < 4; ++rI)
                pv[rI] = (f16)(xnext ? xnext[((size_t)b * TT + tnext) * NN + n0 + rI] : 0.f);
            *(f16x4*)&BfOut[bf_addr(n0, b, 0)] = pv;
        }
    }
}

extern "C" void kernel_launch(void* const* d_in, const int* in_sizes, int n_in,
                              void* d_out, int out_size, void* d_ws, size_t ws_size,
                              hipStream_t stream) {
    const float* x   = (const float*)d_in[0];
    const float* P   = (const float*)d_in[1];
    const float* Weg = (const float*)d_in[2];
    const float* beg = (const float*)d_in[3];
    const float* Weu = (const float*)d_in[4];
    const float* beu = (const float*)d_in[5];
    const float* Wdg = (const float*)d_in[6];
    const float* bdg = (const float*)d_in[7];
    const float* Wdu = (const float*)d_in[8];
    const float* bdu = (const float*)d_in[9];
    const float* Wp  = (const float*)d_in[10];
    const float* bp  = (const float*)d_in[11];
    float* out = (float*)d_out;
    int hor = out_size / (BB * NN);

    float* ws = (float*)d_ws;
    size_t off = 0;
    float* hf = ws + off; off += (size_t)RTOT * HH;
    float* zf = ws + off; off += (size_t)RTOT * HH;
    f16* BfA  = (f16*)(ws + off); off += 16 * 32 * PSUB * 64 * 8 / 2;
    f16* BfB  = (f16*)(ws + off); off += 16 * 32 * PSUB * 64 * 8 / 2;
    f16* Af   = (f16*)(ws + off); off += (size_t)MSUB * 16 * 512 / 2;
    f16* WfGe = (f16*)(ws + off); off += 8 * 8 * 64 * 8 / 2;
    f16* WfGd = (f16*)(ws + off); off += 8 * 8 * 64 * 8 / 2;
    f16* WfCe = (f16*)(ws + off); off += 8 * 4 * 64 * 8 / 2;
    f16* WfCd = (f16*)(ws + off); off += 8 * 4 * 64 * 8 / 2;

    size_t bf_bytes = (size_t)16 * 32 * PSUB * 64 * 8 * sizeof(f16);
    hipMemsetAsync(hf, 0, (size_t)RTOT * HH * sizeof(float), stream);
    hipMemsetAsync(BfA, 0, bf_bytes, stream);
    hipMemsetAsync(BfB, 0, bf_bytes, stream);

    conv_a<<<(MSUB * 16 * 512 / 8) / 256, 256, 0, stream>>>(P, Af);
    conv_w<<<16, 256, 0, stream>>>(Weg, 128, 8, WfGe);
    conv_w<<<16, 256, 0, stream>>>(Wdg, 128, 8, WfGd);
    conv_w<<<8,  256, 0, stream>>>(Weu, 64, 4, WfCe);
    conv_w<<<8,  256, 0, stream>>>(Wdu, 64, 4, WfCd);
    upd_x<<<RTOT / 256, 256, 0, stream>>>(x, 0, BfA);

    for (int t = 0; t < TT; ++t) {
        fused_gates<<<512, 128, 0, stream>>>(Af, BfA, BfB, WfGe, beg, hf, zf);
        fused_cand<<<512, 128, 0, stream>>>(Af, BfB, BfA, WfCe, beu, zf, hf,
                                            (t + 1 < TT) ? x : nullptr, t + 1,
                                            nullptr, nullptr, nullptr, 0, hor, 0);
    }
    for (int t = 0; t < hor; ++t) {
        fused_gates<<<512, 128, 0, stream>>>(Af, BfA, BfB, WfGd, bdg, hf, zf);
        fused_cand<<<512, 128, 0, stream>>>(Af, BfB, BfA, WfCd, bdu, zf, hf,
                                            nullptr, 0,
                                            Wp, bp, out, t, hor, 1);
    }
}

// Round 21
// 511.903 us; speedup vs baseline: 1.9842x; 1.9842x over previous
//
#include <hip/hip_runtime.h>
#include <hip/hip_bf16.h>
#include <math.h>

#define BB 32
#define TT 12
#define NN 512
#define HH 64
#define DIN 65
#define MSUB 96
#define RTOT 16384
#define PSUB 5
#define BSTG 10240     // f16 per B staging buffer (20 subtiles x 512), BK=128
#define WOFF 30720     // 3*BSTG: W region base (f16 units)

typedef _Float16 f16;
typedef f16 f16x4 __attribute__((ext_vector_type(4)));
typedef f16 f16x8 __attribute__((ext_vector_type(8)));
typedef float f32x4 __attribute__((ext_vector_type(4)));

#define GLD_LDS16(g, l) \
    __builtin_amdgcn_global_load_lds((const __attribute__((address_space(1))) void*)(g), \
                                     (__attribute__((address_space(3))) void*)(l), 16, 0, 0)

__device__ __forceinline__ size_t bf_addr(int j, int b, int p) {
    return ((size_t)(((j >> 5) * 32 + b) * PSUB + (p >> 4)) * 64 + ((j >> 3) & 3) * 16 + (p & 15)) * 8 + (j & 7);
}

__global__ __launch_bounds__(256) void conv_a(const float* __restrict__ P, f16* __restrict__ Af) {
    int u = blockIdx.x * 256 + threadIdx.x;
    int lane = u & 63;
    int su = u >> 6;
    int ks = su / MSUB, ms = su - ks * MSUB;
    int m = ms * 16 + (lane & 15);
    int k = ks * 32 + (lane >> 4) * 8;
    const float* src = &P[(size_t)m * 512 + k];
    f16x8 v;
#pragma unroll
    for (int i = 0; i < 8; ++i) v[i] = (f16)src[i];
    *(f16x8*)&Af[(size_t)u * 8] = v;
}

__global__ __launch_bounds__(256) void conv_w(const float* __restrict__ W, int O, int OS,
                                              f16* __restrict__ Wf) {
    int u = blockIdx.x * 256 + threadIdx.x;
    if (u >= 8 * OS * 64) return;
    int lane = u & 63, slot = u >> 6;
    int s = slot / OS, os = slot - s * OS;
    int o = os * 16 + (lane & 15);
    int g = lane >> 4;
    f16x8 v;
#pragma unroll
    for (int i = 0; i < 8; ++i) {
        int f = 2 * s + (i >= 4 ? 1 : 0);
        int kl = f / 5, ps = f - kl * 5;
        int p = ps * 16 + 4 * g + (i & 3);
        v[i] = (f < 15 && p < 65) ? (f16)W[(size_t)(kl * 65 + p) * O + o] : (f16)0.f;
    }
    *(f16x8*)&Wf[(size_t)u * 8] = v;
}

__global__ __launch_bounds__(256) void upd_x(const float* __restrict__ x, int t,
                                             f16* __restrict__ Bf) {
    int idx = blockIdx.x * 256 + threadIdx.x;
    if (idx >= RTOT) return;
    int b = idx >> 9, n = idx & 511;
    Bf[bf_addr(n, b, 0)] = (f16)x[((size_t)b * TT + t) * NN + n];
}

// B staging: 20 subtiles (K128-step), uniform 5 per wave
__device__ __forceinline__ void stage_b(const f16* __restrict__ BfIn, f16* __restrict__ lds,
                                        int b, int wave, int lane, int buf, int it) {
#pragma unroll
    for (int qi = 0; qi < 5; ++qi) {
        int q = qi * 4 + wave;  // 0..19
        int ksl = q / 5, ps = q - ksl * 5;
        const f16* src = &BfIn[((size_t)(((it * 4 + ksl) * 32 + b) * PSUB + ps) * 64 + lane) * 8];
        GLD_LDS16(src, &lds[buf * BSTG + q * 512 + lane * 8]);
    }
}

// A fragments for one K128-step: 12 per wave, direct global->VGPR
__device__ __forceinline__ void load_a(const f16* __restrict__ Af, f16x8 (&a)[12],
                                       int mb, int wave, int lane, int it) {
#pragma unroll
    for (int s = 0; s < 4; ++s)
#pragma unroll
        for (int k = 0; k < 3; ++k)
            a[s * 3 + k] = *(const f16x8*)&Af[((size_t)((it * 4 + s) * MSUB + k * 32 + mb * 4 + wave) * 64 + lane) * 8];
}

__device__ __forceinline__ void compute_step(const f16* __restrict__ lds, int buf, int lane,
                                             const f16x8 (&a)[12], f32x4 (&acc)[15]) {
#pragma unroll
    for (int s = 0; s < 4; ++s) {
        f16x8 bfr[5];
#pragma unroll
        for (int ps = 0; ps < 5; ++ps)
            bfr[ps] = *(const f16x8*)&lds[buf * BSTG + (s * 5 + ps) * 512 + lane * 8];
#pragma unroll
        for (int k = 0; k < 3; ++k)
#pragma unroll
            for (int ps = 0; ps < 5; ++ps)
                acc[k * 5 + ps] = __builtin_amdgcn_mfma_f32_16x16x32_f16(bfr[ps], a[s * 3 + k], acc[k * 5 + ps], 0, 0, 0);
    }
}

// BK=128: 4 K-steps, 3-buffer staging, counted vmcnt, one raw barrier per step.
__device__ __forceinline__ void gcn_mm(const f16* __restrict__ Af,
                                       const f16* __restrict__ BfIn,
                                       f16* __restrict__ lds,
                                       int b, int mb, int wave, int lane,
                                       f32x4 (&acc)[15]) {
    f16x8 a0[12], a1[12];
    stage_b(BfIn, lds, b, wave, lane, 0, 0);
    stage_b(BfIn, lds, b, wave, lane, 1, 1);
    load_a(Af, a0, mb, wave, lane, 0);
#pragma unroll
    for (int it = 0; it < 4; ++it) {
        asm volatile("s_waitcnt vmcnt(12)" ::: "memory");
        __builtin_amdgcn_sched_barrier(0);
        __builtin_amdgcn_s_barrier();
        __builtin_amdgcn_sched_barrier(0);
        if (it + 2 < 4) stage_b(BfIn, lds, b, wave, lane, (it + 2) % 3, it + 2);
        if (it + 1 < 4) {
            if ((it + 1) % 2 == 0) load_a(Af, a0, mb, wave, lane, it + 1);
            else                   load_a(Af, a1, mb, wave, lane, it + 1);
        }
        __builtin_amdgcn_sched_barrier(0);
        if (it % 2 == 0) compute_step(lds, it % 3, lane, a0, acc);
        else             compute_step(lds, it % 3, lane, a1, acc);
    }
}

__device__ __forceinline__ void build_ad(const f32x4 (&acc)[15], f16x8 (&ad)[8]) {
#pragma unroll
    for (int s = 0; s < 8; ++s)
#pragma unroll
        for (int i = 0; i < 4; ++i) {
            ad[s][i] = (f16)acc[2 * s][i];
            ad[s][4 + i] = (s < 7) ? (f16)acc[2 * s + 1][i] : (f16)0.f;
        }
}

// blockIdx = mb*32 + b: XCD = b%8, so Bf rows for batch b stay XCD-local across phases.
__global__ __launch_bounds__(256, 1) void fused_gates(const f16* __restrict__ Af,
                                                      const f16* __restrict__ BfIn,
                                                      f16* __restrict__ BfOut,
                                                      const f16* __restrict__ Wf,
                                                      const float* __restrict__ bias,
                                                      const float* __restrict__ hf,
                                                      float* __restrict__ zf) {
    __shared__ f16 lds[WOFF + 32768];
    int tid = threadIdx.x, wave = tid >> 6, lane = tid & 63;
    int b = blockIdx.x & 31, mb = blockIdx.x >> 5;

    // pre-stage W at entry: latency hides under the whole mm
#pragma unroll
    for (int qi = 0; qi < 16; ++qi) {
        int q = qi * 4 + wave;
        GLD_LDS16(&Wf[((size_t)q * 64 + lane) * 8], &lds[WOFF + q * 512 + lane * 8]);
    }

    f32x4 acc[15] = {};
    gcn_mm(Af, BfIn, lds, b, mb, wave, lane, acc);

    f16x8 ad[8];
    build_ad(acc, ad);

    f32x4 acc2[8] = {};
#pragma unroll
    for (int s = 0; s < 8; ++s)
#pragma unroll
        for (int os = 0; os < 8; ++os) {
            f16x8 w = *(const f16x8*)&lds[WOFF + (s * 8 + os) * 512 + lane * 8];
            acc2[os] = __builtin_amdgcn_mfma_f32_16x16x32_f16(ad[s], w, acc2[os], 0, 0, 0);
        }

    int o_l = lane & 15, g = lane >> 4;
    int node0 = mb * 64 + wave * 16;
    int rf = b * 32 + mb * 4 + wave;
#pragma unroll
    for (int os = 0; os < 4; ++os) {
        f32x4 v;
#pragma unroll
        for (int rI = 0; rI < 4; ++rI)
            v[rI] = 1.f / (1.f + expf(-(acc2[os][rI] + bias[os * 16 + o_l])));
        *(f32x4*)&zf[((size_t)(rf * 4 + os) * 64 + lane) * 4] = v;
    }
#pragma unroll
    for (int os = 4; os < 8; ++os) {
        int osh = os - 4;
        f32x4 hv = *(const f32x4*)&hf[((size_t)(rf * 4 + osh) * 64 + lane) * 4];
        f16x4 st;
#pragma unroll
        for (int rI = 0; rI < 4; ++rI) {
            float rr = 1.f / (1.f + expf(-(acc2[os][rI] + bias[64 + osh * 16 + o_l])));
            st[rI] = (f16)(rr * hv[rI]);
        }
        *(f16x4*)&BfOut[bf_addr(node0 + 4 * g, b, 1 + osh * 16 + o_l)] = st;
    }
    if (tid < 64) {
        int n = mb * 64 + tid;
        BfOut[bf_addr(n, b, 0)] = BfIn[bf_addr(n, b, 0)];
    }
}

__global__ __launch_bounds__(256, 1) void fused_cand(const f16* __restrict__ Af,
                                                     const f16* __restrict__ BfIn,
                                                     f16* __restrict__ BfOut,
                                                     const f16* __restrict__ Wf,
                                                     const float* __restrict__ bias,
                                                     const float* __restrict__ zf,
                                                     float* __restrict__ hf,
                                                     const float* __restrict__ xnext, int tnext,
                                                     const float* __restrict__ Wp,
                                                     const float* __restrict__ bp,
                                                     float* __restrict__ outp, int t, int hor,
                                                     int mode) {
    __shared__ f16 lds[WOFF + 16384];
    int tid = threadIdx.x, wave = tid >> 6, lane = tid & 63;
    int b = blockIdx.x & 31, mb = blockIdx.x >> 5;

#pragma unroll
    for (int qi = 0; qi < 8; ++qi) {
        int q = qi * 4 + wave;
        GLD_LDS16(&Wf[((size_t)q * 64 + lane) * 8], &lds[WOFF + q * 512 + lane * 8]);
    }

    f32x4 acc[15] = {};
    gcn_mm(Af, BfIn, lds, b, mb, wave, lane, acc);

    f16x8 ad[8];
    build_ad(acc, ad);

    f32x4 acc2[4] = {};
#pragma unroll
    for (int s = 0; s < 8; ++s)
#pragma unroll
        for (int os = 0; os < 4; ++os) {
            f16x8 w = *(const f16x8*)&lds[WOFF + (s * 4 + os) * 512 + lane * 8];
            acc2[os] = __builtin_amdgcn_mfma_f32_16x16x32_f16(ad[s], w, acc2[os], 0, 0, 0);
        }

    int o_l = lane & 15, g = lane >> 4;
    int node0 = mb * 64 + wave * 16;
    int rf = b * 32 + mb * 4 + wave;
    float pp[4] = {0.f, 0.f, 0.f, 0.f};
#pragma unroll
    for (int os = 0; os < 4; ++os) {
        int o = os * 16 + o_l;
        float wp = mode ? Wp[o] : 0.f;
        f32x4 zv = *(const f32x4*)&zf[((size_t)(rf * 4 + os) * 64 + lane) * 4];
        f32x4 hv = *(const f32x4*)&hf[((size_t)(rf * 4 + os) * 64 + lane) * 4];
        f32x4 hn;
        f16x4 st;
#pragma unroll
        for (int rI = 0; rI < 4; ++rI) {
            float hc = tanhf(acc2[os][rI] + bias[o]);
            hn[rI] = (1.f - zv[rI]) * hv[rI] + zv[rI] * hc;
            pp[rI] += hn[rI] * wp;
            st[rI] = (f16)hn[rI];
        }
        *(f32x4*)&hf[((size_t)(rf * 4 + os) * 64 + lane) * 4] = hn;
        *(f16x4*)&BfOut[bf_addr(node0 + 4 * g, b, 1 + o)] = st;
    }
    if (mode) {
#pragma unroll
        for (int m = 1; m < 16; m <<= 1)
#pragma unroll
            for (int rI = 0; rI < 4; ++rI) pp[rI] += __shfl_xor(pp[rI], m, 64);
        if (o_l == 0) {
            int n0 = node0 + 4 * g;
            float4 ov;
            f16x4 pv;
            ov.x = pp[0] + bp[0]; ov.y = pp[1] + bp[0];
            ov.z = pp[2] + bp[0]; ov.w = pp[3] + bp[0];
            pv[0] = (f16)ov.x; pv[1] = (f16)ov.y; pv[2] = (f16)ov.z; pv[3] = (f16)ov.w;
            *(float4*)&outp[((size_t)b * hor + t) * NN + n0] = ov;
            *(f16x4*)&BfOut[bf_addr(n0, b, 0)] = pv;
        }
    } else {
        if (o_l == 0) {
            int n0 = node0 + 4 * g;
            f16x4 pv;
#pragma unroll
            for (int rI = 0; rI < 4; ++rI)
                pv[rI] = (f16)(xnext ? xnext[((size_t)b * TT + tnext) * NN + n0 + rI] : 0.f);
            *(f16x4*)&BfOut[bf_addr(n0, b, 0)] = pv;
        }
    }
}

extern "C" void kernel_launch(void* const* d_in, const int* in_sizes, int n_in,
                              void* d_out, int out_size, void* d_ws, size_t ws_size,
                              hipStream_t stream) {
    const float* x   = (const float*)d_in[0];
    const float* P   = (const float*)d_in[1];
    const float* Weg = (const float*)d_in[2];
    const float* beg = (const float*)d_in[3];
    const float* Weu = (const float*)d_in[4];
    const float* beu = (const float*)d_in[5];
    const float* Wdg = (const float*)d_in[6];
    const float* bdg = (const float*)d_in[7];
    const float* Wdu = (const float*)d_in[8];
    const float* bdu = (const float*)d_in[9];
    const float* Wp  = (const float*)d_in[10];
    const float* bp  = (const float*)d_in[11];
    float* out = (float*)d_out;
    int hor = out_size / (BB * NN);

    float* ws = (float*)d_ws;
    size_t off = 0;
    float* hf = ws + off; off += (size_t)RTOT * HH;
    float* zf = ws + off; off += (size_t)RTOT * HH;
    f16* BfA  = (f16*)(ws + off); off += 16 * 32 * PSUB * 64 * 8 / 2;
    f16* BfB  = (f16*)(ws + off); off += 16 * 32 * PSUB * 64 * 8 / 2;
    f16* Af   = (f16*)(ws + off); off += (size_t)MSUB * 16 * 512 / 2;
    f16* WfGe = (f16*)(ws + off); off += 8 * 8 * 64 * 8 / 2;
    f16* WfGd = (f16*)(ws + off); off += 8 * 8 * 64 * 8 / 2;
    f16* WfCe = (f16*)(ws + off); off += 8 * 4 * 64 * 8 / 2;
    f16* WfCd = (f16*)(ws + off); off += 8 * 4 * 64 * 8 / 2;

    size_t bf_bytes = (size_t)16 * 32 * PSUB * 64 * 8 * sizeof(f16);
    hipMemsetAsync(hf, 0, (size_t)RTOT * HH * sizeof(float), stream);
    hipMemsetAsync(BfA, 0, bf_bytes, stream);
    hipMemsetAsync(BfB, 0, bf_bytes, stream);

    conv_a<<<(MSUB * 16 * 512 / 8) / 256, 256, 0, stream>>>(P, Af);
    conv_w<<<16, 256, 0, stream>>>(Weg, 128, 8, WfGe);
    conv_w<<<16, 256, 0, stream>>>(Wdg, 128, 8, WfGd);
    conv_w<<<8,  256, 0, stream>>>(Weu, 64, 4, WfCe);
    conv_w<<<8,  256, 0, stream>>>(Wdu, 64, 4, WfCd);
    upd_x<<<RTOT / 256, 256, 0, stream>>>(x, 0, BfA);

    for (int t = 0; t < TT; ++t) {
        fused_gates<<<256, 256, 0, stream>>>(Af, BfA, BfB, WfGe, beg, hf, zf);
        fused_cand<<<256, 256, 0, stream>>>(Af, BfB, BfA, WfCe, beu, zf, hf,
                                            (t + 1 < TT) ? x : nullptr, t + 1,
                                            nullptr, nullptr, nullptr, 0, hor, 0);
    }
    for (int t = 0; t < hor; ++t) {
        fused_gates<<<256, 256, 0, stream>>>(Af, BfA, BfB, WfGd, bdg, hf, zf);
        fused_cand<<<256, 256, 0, stream>>>(Af, BfB, BfA, WfCd, bdu, zf, hf,
                                            nullptr, 0,
                                            Wp, bp, out, t, hor, 1);
    }
}